// Round 1
// baseline (2569.806 us; speedup 1.0000x reference)
//
#include <hip/hip_runtime.h>

#define D 128

__device__ __forceinline__ float4 f4zero() { return make_float4(0.f, 0.f, 0.f, 0.f); }

#define FMA4(accv, s, wv) \
    (accv).x += (s) * (wv).x; (accv).y += (s) * (wv).y; \
    (accv).z += (s) * (wv).z; (accv).w += (s) * (wv).w;

// MODE 0: C = relu(A@W + bias)           (node projection -> nf2)
// MODE 1: C = 0.5f * (A@W)               (Q = 0.5*nf2@W2)
// MODE 2: C = A@W; sG[dst[row]] += C[row]; deg[dst[row]] += 1   (edge GEMM + scatter)
template <int MODE>
__global__ __launch_bounds__(256) void gemm128(
    const float* __restrict__ A, const float* __restrict__ W,
    const float* __restrict__ bias, float* __restrict__ C, int M,
    const int* __restrict__ dst, float* __restrict__ sG, float* __restrict__ deg)
{
    __shared__ float Wl[128 * 128];   // 64 KB
    __shared__ float At[128 * 64];    // 32 KB  (A^T tile: At[k][r])

    const int tid = threadIdx.x;
    const int row0 = blockIdx.x * 64;

    // ---- stage W into LDS (coalesced float4) ----
    {
        const float4* W4 = (const float4*)W;
        float4* Wl4 = (float4*)Wl;
#pragma unroll
        for (int i = 0; i < 16; ++i) Wl4[tid + i * 256] = W4[tid + i * 256];
    }
    // ---- stage A^T tile: thread r = tid&63 owns one row ----
    {
        const int r = tid & 63;
        const int row = row0 + r;
        const bool ok = (row < M);
        const float4* Arow = (const float4*)(A + (size_t)row * D);
#pragma unroll
        for (int kg = tid >> 6; kg < 32; kg += 4) {
            float4 v = ok ? Arow[kg] : f4zero();
            At[(kg * 4 + 0) * 64 + r] = v.x;
            At[(kg * 4 + 1) * 64 + r] = v.y;
            At[(kg * 4 + 2) * 64 + r] = v.z;
            At[(kg * 4 + 3) * 64 + r] = v.w;
        }
    }
    __syncthreads();

    const int tc = tid & 15;   // col group: cols [4tc..4tc+3] and [64+4tc..64+4tc+3]
    const int tr = tid >> 4;   // row group: rows 4tr..4tr+3

    float4 acc[4][2];
#pragma unroll
    for (int i = 0; i < 4; ++i) { acc[i][0] = f4zero(); acc[i][1] = f4zero(); }

#pragma unroll 2
    for (int k = 0; k < 128; ++k) {
        const float4 a  = *(const float4*)&At[k * 64 + 4 * tr];
        const float4 w0 = *(const float4*)&Wl[k * 128 + 4 * tc];
        const float4 w1 = *(const float4*)&Wl[k * 128 + 64 + 4 * tc];
        FMA4(acc[0][0], a.x, w0); FMA4(acc[0][1], a.x, w1);
        FMA4(acc[1][0], a.y, w0); FMA4(acc[1][1], a.y, w1);
        FMA4(acc[2][0], a.z, w0); FMA4(acc[2][1], a.z, w1);
        FMA4(acc[3][0], a.w, w0); FMA4(acc[3][1], a.w, w1);
    }

    float4 b0 = f4zero(), b1 = f4zero();
    if (MODE == 0) {
        b0 = ((const float4*)bias)[tc];
        b1 = ((const float4*)bias)[16 + tc];
    }

#pragma unroll
    for (int i = 0; i < 4; ++i) {
        const int row = row0 + 4 * tr + i;
        if (row >= M) continue;
        float4 v0 = acc[i][0], v1 = acc[i][1];
        if (MODE == 0) {
            v0.x = fmaxf(v0.x + b0.x, 0.f); v0.y = fmaxf(v0.y + b0.y, 0.f);
            v0.z = fmaxf(v0.z + b0.z, 0.f); v0.w = fmaxf(v0.w + b0.w, 0.f);
            v1.x = fmaxf(v1.x + b1.x, 0.f); v1.y = fmaxf(v1.y + b1.y, 0.f);
            v1.z = fmaxf(v1.z + b1.z, 0.f); v1.w = fmaxf(v1.w + b1.w, 0.f);
        }
        if (MODE == 1) {
            v0.x *= 0.5f; v0.y *= 0.5f; v0.z *= 0.5f; v0.w *= 0.5f;
            v1.x *= 0.5f; v1.y *= 0.5f; v1.z *= 0.5f; v1.w *= 0.5f;
        }
        float4* Crow = (float4*)(C + (size_t)row * D);
        Crow[tc] = v0;
        Crow[16 + tc] = v1;
        if (MODE == 2) {
            const int d = dst[row];
            float* srow = sG + (size_t)d * D;
            atomicAdd(&srow[4 * tc + 0], v0.x);
            atomicAdd(&srow[4 * tc + 1], v0.y);
            atomicAdd(&srow[4 * tc + 2], v0.z);
            atomicAdd(&srow[4 * tc + 3], v0.w);
            atomicAdd(&srow[64 + 4 * tc + 0], v1.x);
            atomicAdd(&srow[64 + 4 * tc + 1], v1.y);
            atomicAdd(&srow[64 + 4 * tc + 2], v1.z);
            atomicAdd(&srow[64 + 4 * tc + 3], v1.w);
            if (tc == 0) atomicAdd(&deg[d], 1.0f);
        }
    }
}

// W_combo = W_edge @ dense_W[0:128,:]   (128x128 @ 128x128, tiny)
__global__ __launch_bounds__(256) void wcombo_k(
    const float* __restrict__ We, const float* __restrict__ dW, float* __restrict__ out)
{
    const int i = blockIdx.x * 2 + (threadIdx.x >> 7);
    const int j = threadIdx.x & 127;
    float acc = 0.f;
#pragma unroll 4
    for (int k = 0; k < 128; ++k) acc += We[i * 128 + k] * dW[k * 128 + j];
    out[i * 128 + j] = acc;
}

// ef2[e] = relu(G[e] + sG[dst]/max(deg,1) + Q[src] + Q[dst] + dense_b + edge_bias), in place on G
__global__ __launch_bounds__(256) void edge_final(
    float* __restrict__ G, const float* __restrict__ sG, const float* __restrict__ deg,
    const float* __restrict__ Q, const int* __restrict__ src, const int* __restrict__ dst,
    const float* __restrict__ dense_b, const float* __restrict__ edge_bias, int E)
{
    const int e = blockIdx.x * 8 + (threadIdx.x >> 5);
    const int c = threadIdx.x & 31;   // float4 index 0..31
    if (e >= E) return;
    const int d = dst[e];
    const int s = src[e];
    const float r = 1.0f / fmaxf(deg[d], 1.0f);

    float4* Grow = (float4*)(G + (size_t)e * D);
    const float4 g  = Grow[c];
    const float4 sg = ((const float4*)(sG + (size_t)d * D))[c];
    const float4 qs = ((const float4*)(Q + (size_t)s * D))[c];
    const float4 qd = ((const float4*)(Q + (size_t)d * D))[c];
    const float4 b  = ((const float4*)dense_b)[c];
    const float4 eb = ((const float4*)edge_bias)[c];

    float4 o;
    o.x = fmaxf(g.x + sg.x * r + qs.x + qd.x + b.x + eb.x, 0.f);
    o.y = fmaxf(g.y + sg.y * r + qs.y + qd.y + b.y + eb.y, 0.f);
    o.z = fmaxf(g.z + sg.z * r + qs.z + qd.z + b.z + eb.z, 0.f);
    o.w = fmaxf(g.w + sg.w * r + qs.w + qd.w + b.w + eb.w, 0.f);
    Grow[c] = o;
}

extern "C" void kernel_launch(void* const* d_in, const int* in_sizes, int n_in,
                              void* d_out, int out_size, void* d_ws, size_t ws_size,
                              hipStream_t stream)
{
    const float* nf        = (const float*)d_in[0];
    const float* ef        = (const float*)d_in[1];
    const float* W_node    = (const float*)d_in[2];
    const float* W_edge    = (const float*)d_in[3];
    const float* node_bias = (const float*)d_in[4];
    const float* edge_bias = (const float*)d_in[5];
    const float* dense_W   = (const float*)d_in[6];
    const float* dense_b   = (const float*)d_in[7];
    const int*   src       = (const int*)d_in[8];
    const int*   dst       = (const int*)d_in[9];

    const int N = in_sizes[0] / D;
    const int E = in_sizes[1] / D;

    float* out_nf2 = (float*)d_out;
    float* G       = (float*)d_out + (size_t)N * D;   // ef2 region doubles as G scratch

    float* ws     = (float*)d_ws;
    float* wcombo = ws;                               // 128*128
    float* Q      = wcombo + 128 * 128;               // N*D
    float* sG     = Q + (size_t)N * D;                // N*D
    float* deg    = sG + (size_t)N * D;               // N

    hipMemsetAsync(sG, 0, (size_t)N * D * sizeof(float), stream);
    hipMemsetAsync(deg, 0, (size_t)N * sizeof(float), stream);

    wcombo_k<<<64, 256, 0, stream>>>(W_edge, dense_W, wcombo);

    // nf2 = relu(nf @ W_node + node_bias)
    gemm128<0><<<(N + 63) / 64, 256, 0, stream>>>(
        nf, W_node, node_bias, out_nf2, N, nullptr, nullptr, nullptr);
    // Q = 0.5 * nf2 @ W2
    gemm128<1><<<(N + 63) / 64, 256, 0, stream>>>(
        out_nf2, dense_W + 128 * 128, nullptr, Q, N, nullptr, nullptr, nullptr);
    // G = ef @ W_combo ; sG[dst] += G ; deg[dst] += 1
    gemm128<2><<<(E + 63) / 64, 256, 0, stream>>>(
        ef, wcombo, nullptr, G, E, dst, sG, deg);
    // ef2 = relu(G + sG[dst]/max(deg,1) + Q[src] + Q[dst] + biases)
    edge_final<<<(E + 7) / 8, 256, 0, stream>>>(
        G, sG, deg, Q, src, dst, dense_b, edge_bias, E);
}

// Round 2
// 2190.342 us; speedup vs baseline: 1.1732x; 1.1732x over previous
//
#include <hip/hip_runtime.h>

#define D 128

__device__ __forceinline__ float4 f4zero() { return make_float4(0.f, 0.f, 0.f, 0.f); }

#define FMA4(accv, s, wv) \
    (accv).x = fmaf((s), (wv).x, (accv).x); (accv).y = fmaf((s), (wv).y, (accv).y); \
    (accv).z = fmaf((s), (wv).z, (accv).z); (accv).w = fmaf((s), (wv).w, (accv).w);

#define ADD4(o, a, b) \
    (o).x = (a).x + (b).x; (o).y = (a).y + (b).y; (o).z = (a).z + (b).z; (o).w = (a).w + (b).w;

// GEMM modes
#define M_NODE 0   // C = relu(A@W + bias)
#define M_HALF 1   // C = 0.5*(A@W)
#define M_RQ   2   // C = A@W + Q[row] + b1 + b2        (in-place safe: C may == A)
#define M_EDGE 3   // C = relu(A@W + R[dst[row]] + Q[src[row]])

// 512 threads = 8 waves. Block tile: 256 rows x 128 cols.
// wave -> (rowWave 0..1, colWave 0..3); lane owns rows (base+lane, base+lane+64), 32 cols.
// Only W lives in LDS (64 KB -> 2 blocks/CU -> 16 waves/CU). W reads are same-address
// b128 broadcasts (conflict-free). A read per-lane from global (row-major, L1 reuse).
template <int MODE>
__global__ __launch_bounds__(512, 4) void gemm_v(
    const float* __restrict__ A, const float* __restrict__ W, float* __restrict__ C, int M,
    const float* __restrict__ bias,
    const float* __restrict__ R, const float* __restrict__ Q,
    const int* __restrict__ src, const int* __restrict__ dst,
    const float* __restrict__ b1, const float* __restrict__ b2)
{
    __shared__ float Wl[D * D];   // 64 KB
    const int tid = threadIdx.x;
    {
        const float4* W4 = (const float4*)W;
        float4* Wl4 = (float4*)Wl;
#pragma unroll
        for (int i = 0; i < 8; ++i) Wl4[tid + i * 512] = W4[tid + i * 512];
    }
    __syncthreads();

    const int lane = tid & 63;
    const int wv = tid >> 6;
    const int rowWave = wv >> 2;
    const int colBase = (wv & 3) * 32;

    const int r0 = blockIdx.x * 256 + rowWave * 128 + lane;
    const int r1 = r0 + 64;
    const bool ok0 = (r0 < M), ok1 = (r1 < M);
    const float* A0 = A + (size_t)(ok0 ? r0 : 0) * D;   // clamp addr; store is guarded
    const float* A1 = A + (size_t)(ok1 ? r1 : 0) * D;

    float4 acc0[8], acc1[8];
#pragma unroll
    for (int j = 0; j < 8; ++j) { acc0[j] = f4zero(); acc1[j] = f4zero(); }

#pragma unroll 2
    for (int k = 0; k < D; k += 4) {
        const float4 a0 = *(const float4*)(A0 + k);
        const float4 a1 = *(const float4*)(A1 + k);
#pragma unroll
        for (int kk = 0; kk < 4; ++kk) {
            const float av0 = (&a0.x)[kk];
            const float av1 = (&a1.x)[kk];
            const float* wrow = &Wl[(k + kk) * D + colBase];
#pragma unroll
            for (int j = 0; j < 8; ++j) {
                const float4 w = *(const float4*)(wrow + 4 * j);
                FMA4(acc0[j], av0, w);
                FMA4(acc1[j], av1, w);
            }
        }
    }

    __syncthreads();   // in-place safety for M_RQ (all A reads done before any C write)

#pragma unroll
    for (int rr = 0; rr < 2; ++rr) {
        const int row = rr ? r1 : r0;
        if (!(rr ? ok1 : ok0)) continue;
        float4* accp = rr ? acc1 : acc0;
        float4* Crow = (float4*)(C + (size_t)row * D + colBase);
        if (MODE == M_NODE) {
            const float4* B = (const float4*)bias + (colBase >> 2);
#pragma unroll
            for (int j = 0; j < 8; ++j) {
                float4 v; ADD4(v, accp[j], B[j]);
                v.x = fmaxf(v.x, 0.f); v.y = fmaxf(v.y, 0.f);
                v.z = fmaxf(v.z, 0.f); v.w = fmaxf(v.w, 0.f);
                Crow[j] = v;
            }
        } else if (MODE == M_HALF) {
#pragma unroll
            for (int j = 0; j < 8; ++j) {
                float4 v = accp[j];
                v.x *= 0.5f; v.y *= 0.5f; v.z *= 0.5f; v.w *= 0.5f;
                Crow[j] = v;
            }
        } else if (MODE == M_RQ) {
            const float4* Qr = (const float4*)(Q + (size_t)row * D + colBase);
            const float4* B1 = (const float4*)b1 + (colBase >> 2);
            const float4* B2 = (const float4*)b2 + (colBase >> 2);
#pragma unroll
            for (int j = 0; j < 8; ++j) {
                float4 v; ADD4(v, accp[j], Qr[j]);
                float4 bb; ADD4(bb, B1[j], B2[j]);
                ADD4(v, v, bb);
                Crow[j] = v;
            }
        } else { // M_EDGE
            const int d = dst[row];
            const int s = src[row];
            const float4* RQr = (const float4*)(R + (size_t)d * D + colBase);
            const float4* Qs  = (const float4*)(Q + (size_t)s * D + colBase);
#pragma unroll
            for (int j = 0; j < 8; ++j) {
                float4 v; ADD4(v, accp[j], RQr[j]);
                ADD4(v, v, Qs[j]);
                v.x = fmaxf(v.x, 0.f); v.y = fmaxf(v.y, 0.f);
                v.z = fmaxf(v.z, 0.f); v.w = fmaxf(v.w, 0.f);
                Crow[j] = v;
            }
        }
    }
}

// W_combo = W_edge @ dense_W[0:128,:]
__global__ __launch_bounds__(256) void wcombo_k(
    const float* __restrict__ We, const float* __restrict__ dW, float* __restrict__ out)
{
    const int i = blockIdx.x * 2 + (threadIdx.x >> 7);
    const int j = threadIdx.x & 127;
    float acc = 0.f;
#pragma unroll 4
    for (int k = 0; k < D; ++k) acc = fmaf(We[i * D + k], dW[k * D + j], acc);
    out[i * D + j] = acc;
}

__global__ __launch_bounds__(256) void hist_k(const int* __restrict__ dst,
                                              int* __restrict__ cnt, int E)
{
    const int e = blockIdx.x * 256 + threadIdx.x;
    if (e < E) atomicAdd(&cnt[dst[e]], 1);
}

// single-block exclusive scan over cnt[0..N) -> rowptr (N+1) and cursor copy
__global__ __launch_bounds__(1024) void scan_k(const int* __restrict__ cnt,
                                               int* __restrict__ rowptr,
                                               int* __restrict__ cursor, int N, int E)
{
    __shared__ int wsum[16];
    __shared__ int woff[16];
    __shared__ int tot_s;
    __shared__ int carry_s;
    const int tid = threadIdx.x, lane = tid & 63, wv = tid >> 6;
    if (tid == 0) carry_s = 0;
    __syncthreads();
    for (int base = 0; base < N; base += 1024) {
        const int i = base + tid;
        const int v = (i < N) ? cnt[i] : 0;
        int x = v;
#pragma unroll
        for (int off = 1; off < 64; off <<= 1) {
            int t = __shfl_up(x, off);
            if (lane >= off) x += t;
        }
        if (lane == 63) wsum[wv] = x;
        __syncthreads();
        if (wv == 0) {
            int s = (lane < 16) ? wsum[lane] : 0;
#pragma unroll
            for (int off = 1; off < 16; off <<= 1) {
                int t = __shfl_up(s, off);
                if (lane >= off) s += t;
            }
            if (lane < 16) woff[lane] = s - wsum[lane];
            if (lane == 15) tot_s = s;
        }
        __syncthreads();
        const int excl = x - v + woff[wv] + carry_s;
        if (i < N) { rowptr[i] = excl; cursor[i] = excl; }
        __syncthreads();
        if (tid == 0) carry_s += tot_s;
        __syncthreads();
    }
    if (tid == 0) rowptr[N] = E;
}

__global__ __launch_bounds__(256) void scatter_k(const int* __restrict__ dst,
                                                 int* __restrict__ cursor,
                                                 int* __restrict__ eidx, int E)
{
    const int e = blockIdx.x * 256 + threadIdx.x;
    if (e < E) {
        const int p = atomicAdd(&cursor[dst[e]], 1);
        eidx[p] = e;
    }
}

// Sn[n] = (sum of ef rows with dst==n) / max(deg,1)   — CSR gather, no atomics
__global__ __launch_bounds__(256) void segsum_k(const float* __restrict__ ef,
                                                const int* __restrict__ rowptr,
                                                const int* __restrict__ eidx,
                                                float* __restrict__ Sn)
{
    const int n = blockIdx.x;
    const int start = rowptr[n], end = rowptr[n + 1];
    const int c = threadIdx.x & 31;    // float4 column
    const int slot = threadIdx.x >> 5; // 0..7
    float4 acc = f4zero();
    for (int i = start + slot; i < end; i += 8) {
        const int e = eidx[i];
        const float4 v = ((const float4*)ef)[(size_t)e * 32 + c];
        ADD4(acc, acc, v);
    }
    __shared__ float4 red[8][32];
    red[slot][c] = acc;
    __syncthreads();
    if (slot == 0) {
        float4 s = red[0][c];
#pragma unroll
        for (int r = 1; r < 8; ++r) { ADD4(s, s, red[r][c]); }
        const float inv = 1.0f / fmaxf((float)(end - start), 1.0f);
        s.x *= inv; s.y *= inv; s.z *= inv; s.w *= inv;
        ((float4*)Sn)[(size_t)n * 32 + c] = s;
    }
}

extern "C" void kernel_launch(void* const* d_in, const int* in_sizes, int n_in,
                              void* d_out, int out_size, void* d_ws, size_t ws_size,
                              hipStream_t stream)
{
    const float* nf        = (const float*)d_in[0];
    const float* ef        = (const float*)d_in[1];
    const float* W_node    = (const float*)d_in[2];
    const float* W_edge    = (const float*)d_in[3];
    const float* node_bias = (const float*)d_in[4];
    const float* edge_bias = (const float*)d_in[5];
    const float* dense_W   = (const float*)d_in[6];
    const float* dense_b   = (const float*)d_in[7];
    const int*   src       = (const int*)d_in[8];
    const int*   dst       = (const int*)d_in[9];

    const int N = in_sizes[0] / D;
    const int E = in_sizes[1] / D;

    float* out_nf2 = (float*)d_out;
    float* out_ef2 = (float*)d_out + (size_t)N * D;

    float* wcombo = (float*)d_ws;                 // 128*128
    float* Q      = wcombo + D * D;               // N*D  (0.5*nf2@W2)
    float* SnRQ   = Q + (size_t)N * D;            // N*D  (Sn, then RQ in place)
    int*   cnt    = (int*)(SnRQ + (size_t)N * D); // N
    int*   rowptr = cnt + N;                      // N+1
    int*   cursor = rowptr + N + 1;               // N
    int*   eidx   = cursor + N;                   // E

    hipMemsetAsync(cnt, 0, (size_t)N * sizeof(int), stream);

    wcombo_k<<<64, 256, 0, stream>>>(W_edge, dense_W, wcombo);

    // nf2 = relu(nf @ W_node + node_bias)
    gemm_v<M_NODE><<<(N + 255) / 256, 512, 0, stream>>>(
        nf, W_node, out_nf2, N, node_bias, nullptr, nullptr, nullptr, nullptr, nullptr, nullptr);
    // Q = 0.5 * nf2 @ W2
    gemm_v<M_HALF><<<(N + 255) / 256, 512, 0, stream>>>(
        out_nf2, dense_W + D * D, Q, N, nullptr, nullptr, nullptr, nullptr, nullptr, nullptr, nullptr);

    // CSR by dst
    hist_k<<<(E + 255) / 256, 256, 0, stream>>>(dst, cnt, E);
    scan_k<<<1, 1024, 0, stream>>>(cnt, rowptr, cursor, N, E);
    scatter_k<<<(E + 255) / 256, 256, 0, stream>>>(dst, cursor, eidx, E);

    // Sn = segsum(ef)/deg
    segsum_k<<<N, 256, 0, stream>>>(ef, rowptr, eidx, SnRQ);

    // RQ = Sn@Wc + Q + dense_b + edge_bias   (in place on Sn)
    gemm_v<M_RQ><<<(N + 255) / 256, 512, 0, stream>>>(
        SnRQ, wcombo, SnRQ, N, nullptr, nullptr, Q, nullptr, nullptr, dense_b, edge_bias);

    // ef2 = relu(ef@Wc + RQ[dst] + Q[src])
    gemm_v<M_EDGE><<<(E + 255) / 256, 512, 0, stream>>>(
        ef, wcombo, out_ef2, E, nullptr, SnRQ, Q, src, dst, nullptr, nullptr);
}